// Round 8
// baseline (526.517 us; speedup 1.0000x reference)
//
#include <hip/hip_runtime.h>
#include <math.h>

#define NT 100000
#define ET 1600000
#define GT 128

typedef float f4 __attribute__((ext_vector_type(4)));

__device__ __forceinline__ float lrelu(float v) { return v > 0.0f ? v : 0.2f * v; }
__device__ __forceinline__ float elu1(float v) { return v > 0.0f ? v : __expf(v) - 1.0f; }

// ---------------- CSR build ----------------
__global__ void k_count(const int* __restrict__ dst, int* __restrict__ counts) {
  int e = blockIdx.x * 256 + threadIdx.x;
  if (e < ET) atomicAdd(&counts[dst[e]], 1);
}

__global__ __launch_bounds__(256) void k_scan1(const int* __restrict__ counts,
                                               int* __restrict__ scanned,
                                               int* __restrict__ partials) {
  __shared__ int sh[256];
  int t = threadIdx.x;
  int base = blockIdx.x * 1024 + t * 4;
  int v[4];
#pragma unroll
  for (int i = 0; i < 4; ++i) v[i] = (base + i < NT) ? counts[base + i] : 0;
  int tsum = v[0] + v[1] + v[2] + v[3];
  sh[t] = tsum;
  __syncthreads();
  for (int off = 1; off < 256; off <<= 1) {
    int xv = (t >= off) ? sh[t - off] : 0;
    __syncthreads();
    sh[t] += xv;
    __syncthreads();
  }
  int ex = sh[t] - tsum;
#pragma unroll
  for (int i = 0; i < 4; ++i) {
    if (base + i < NT) scanned[base + i] = ex;
    ex += v[i];
  }
  if (t == 255) partials[blockIdx.x] = sh[255];
}

__global__ void k_scan2(int* partials) {
  if (threadIdx.x == 0) {
    int s = 0;
    for (int i = 0; i < 98; ++i) { int v = partials[i]; partials[i] = s; s += v; }
    partials[98] = s;
  }
}

__global__ void k_scan3(int* __restrict__ rp, int* __restrict__ cursor,
                        const int* __restrict__ partials) {
  int i = blockIdx.x * 256 + threadIdx.x;
  if (i < NT) {
    int v = rp[i] + partials[i >> 10];
    rp[i] = v;
    cursor[i] = v;
    if (i == 0) rp[NT] = ET;
  }
}

__global__ void k_scatter(const int* __restrict__ src, const int* __restrict__ dst,
                          int* __restrict__ cursor, int* __restrict__ adj) {
  int e = blockIdx.x * 256 + threadIdx.x;
  if (e < ET) {
    int pos = atomicAdd(&cursor[dst[e]], 1);
    adj[pos] = src[e];
  }
}

// ---------------- prep: AB[k][j] = sum_c W1[k][h*32+c] * a[h][c]  (j<4: src, j>=4: dst) ----------------
__global__ void k_prep(const float* __restrict__ W1, const float* __restrict__ as1,
                       const float* __restrict__ ad1, float* __restrict__ AB) {
  int t = threadIdx.x;  // 256
  int k = t >> 3, j = t & 7;
  const float* a = (j < 4) ? as1 : ad1;
  int h = j & 3;
  float s = 0.0f;
  for (int c = 0; c < 32; ++c) s += W1[k * 128 + h * 32 + c] * a[h * 32 + c];
  AB[t] = s;  // AB[k*8 + j]
}

// ---------------- att1: es1/ed1 = x @ AB (N x 32 x 8) ----------------
__global__ __launch_bounds__(256) void k_att1(const float* __restrict__ x, const float* __restrict__ AB,
                                              float* __restrict__ es, float* __restrict__ ed) {
  __shared__ float xsh[32 * 33];
  __shared__ float absh[256];
  int t = threadIdx.x;
  int n0 = blockIdx.x * 32;
  absh[t] = AB[t];
  for (int i = t; i < 1024; i += 256) {
    int ln = i >> 5, k = i & 31;
    int node = n0 + ln;
    xsh[ln * 33 + k] = (node < NT) ? x[node * 32 + k] : 0.0f;
  }
  __syncthreads();
  int ln = t >> 3, j = t & 7;
  int node = n0 + ln;
  if (node < NT) {
    float s = 0.0f;
#pragma unroll
    for (int k = 0; k < 32; ++k) s += xsh[ln * 33 + k] * absh[k * 8 + j];
    if (j < 4) es[node * 4 + j] = s;
    else ed[node * 4 + (j - 4)] = s;
  }
}

// ---------------- agg1f: fused L1 aggregate (input space) + L1 matvec + ELU + L2 GEMM + L2 logits ----------------
// 16 nodes per block (4 per wave, wave-local loop). W1/W2/b1/a2 staged in LDS once.
// SoA scalar weight buffers (no LDS bank conflicts).
__global__ __launch_bounds__(256) void k_agg1f(
    const int* __restrict__ rp, const int* __restrict__ adj,
    const float* __restrict__ es, const float* __restrict__ ed,
    const float* __restrict__ x,
    const float* __restrict__ W1, const float* __restrict__ b1,
    const float* __restrict__ W2,
    const float* __restrict__ as2, const float* __restrict__ ad2,
    float* __restrict__ h2, float* __restrict__ es2, float* __restrict__ ed2) {
  __shared__ float W1sh[4096];   // [k*128+c], k<32
  __shared__ float W2sh[4096];   // [k*32+c],  k<128
  __shared__ float b1sh[128], as2sh[32], ad2sh[32];
  __shared__ int sbuf_all[4][66];
  __shared__ float wsh_all[4][4][66];   // [wave][head][edge]
  __shared__ float ysh_all[4][128];
  __shared__ float osh_all[4][128];
  int t = threadIdx.x;
  for (int i = t; i < 4096; i += 256) W1sh[i] = W1[i];
  for (int i = t; i < 4096; i += 256) W2sh[i] = W2[i];
  if (t < 128) b1sh[t] = b1[t];
  else if (t < 160) as2sh[t - 128] = as2[t - 128];
  else if (t < 192) ad2sh[t - 160] = ad2[t - 160];
  __syncthreads();

  int wv = t >> 6, l = t & 63;
  int* sbuf = sbuf_all[wv];
  float* w0 = wsh_all[wv][0];
  float* w1w = wsh_all[wv][1];
  float* w2w = wsh_all[wv][2];
  float* w3w = wsh_all[wv][3];
  float* ysh = ysh_all[wv];
  float* osh = osh_all[wv];
  const f4* es4 = (const f4*)es;
  int eg = l >> 3, q = l & 7;

  for (int nn = 0; nn < 4; ++nn) {
    int n = blockIdx.x * 16 + nn * 4 + wv;
    if (n >= NT) break;
    int rs = rp[n], re = rp[n + 1];
    int deg = re - rs;
    f4 edn = ((const f4*)ed)[n];
    f4 esn = es4[n];
    float edna[4], vs[4];
#pragma unroll
    for (int h = 0; h < 4; ++h) { edna[h] = edn[h]; vs[h] = lrelu(esn[h] + edn[h]); }
    f4 a0 = {0,0,0,0}, a1 = {0,0,0,0}, a2 = {0,0,0,0}, a3 = {0,0,0,0};

    if (deg <= 64) {
      float v[4];
      if (l < deg) {
        int s = adj[rs + l];
        sbuf[l] = s;
        f4 ev = es4[s];
#pragma unroll
        for (int h = 0; h < 4; ++h) v[h] = lrelu(ev[h] + edna[h]);
      } else {
#pragma unroll
        for (int h = 0; h < 4; ++h) v[h] = -1e30f;
      }
      float m[4];
#pragma unroll
      for (int h = 0; h < 4; ++h) m[h] = v[h];
#pragma unroll
      for (int off = 1; off <= 32; off <<= 1)
#pragma unroll
        for (int h = 0; h < 4; ++h) m[h] = fmaxf(m[h], __shfl_xor(m[h], off));
#pragma unroll
      for (int h = 0; h < 4; ++h) m[h] = fmaxf(m[h], vs[h]);
      float ex[4], d[4];
#pragma unroll
      for (int h = 0; h < 4; ++h) { ex[h] = (l < deg) ? __expf(v[h] - m[h]) : 0.0f; d[h] = ex[h]; }
#pragma unroll
      for (int off = 1; off <= 32; off <<= 1)
#pragma unroll
        for (int h = 0; h < 4; ++h) d[h] += __shfl_xor(d[h], off);
      float inv[4], wself[4];
#pragma unroll
      for (int h = 0; h < 4; ++h) {
        float sv = __expf(vs[h] - m[h]);
        inv[h] = 1.0f / (d[h] + sv);
        wself[h] = sv * inv[h];
      }
      if (l < deg) {
        w0[l] = ex[0] * inv[0];
        w1w[l] = ex[1] * inv[1];
        w2w[l] = ex[2] * inv[2];
        w3w[l] = ex[3] * inv[3];
      }
      if (l == 0) {
        sbuf[deg] = n;
        w0[deg] = wself[0]; w1w[deg] = wself[1]; w2w[deg] = wself[2]; w3w[deg] = wself[3];
      }
      __builtin_amdgcn_wave_barrier();
      for (int e = eg; e <= deg; e += 8) {
        f4 xv = *(const f4*)&x[sbuf[e] * 32 + 4 * q];
        a0 += w0[e] * xv; a1 += w1w[e] * xv; a2 += w2w[e] * xv; a3 += w3w[e] * xv;
      }
    } else {
      // generic path (deg > 64, rare)
      float m[4], den[4];
#pragma unroll
      for (int h = 0; h < 4; ++h) { m[h] = -1e30f; den[h] = 0.0f; }
      for (int j = rs + l; j < re; j += 64) {
        int s = adj[j];
        f4 ev = es4[s];
#pragma unroll
        for (int h = 0; h < 4; ++h) {
          float v = lrelu(ev[h] + edna[h]);
          if (v > m[h]) { den[h] = den[h] * __expf(m[h] - v) + 1.0f; m[h] = v; }
          else den[h] += __expf(v - m[h]);
        }
      }
#pragma unroll
      for (int off = 1; off <= 32; off <<= 1) {
#pragma unroll
        for (int h = 0; h < 4; ++h) {
          float m2 = __shfl_xor(m[h], off), d2 = __shfl_xor(den[h], off);
          float mm = fmaxf(m[h], m2);
          den[h] = den[h] * __expf(m[h] - mm) + d2 * __expf(m2 - mm);
          m[h] = mm;
        }
      }
      float inv[4], wself[4];
#pragma unroll
      for (int h = 0; h < 4; ++h) {
        float mm = fmaxf(m[h], vs[h]);
        float dd = den[h] * __expf(m[h] - mm) + __expf(vs[h] - mm);
        m[h] = mm;
        inv[h] = 1.0f / dd;
        wself[h] = __expf(vs[h] - mm) * inv[h];
      }
      for (int base = rs; base < re; base += 64) {
        int cnt = min(64, re - base);
        if (l < cnt) {
          int s = adj[base + l];
          sbuf[l] = s;
          f4 ev = es4[s];
          w0[l] = __expf(lrelu(ev[0] + edna[0]) - m[0]) * inv[0];
          w1w[l] = __expf(lrelu(ev[1] + edna[1]) - m[1]) * inv[1];
          w2w[l] = __expf(lrelu(ev[2] + edna[2]) - m[2]) * inv[2];
          w3w[l] = __expf(lrelu(ev[3] + edna[3]) - m[3]) * inv[3];
        }
        __builtin_amdgcn_wave_barrier();
        for (int e = eg; e < cnt; e += 8) {
          f4 xv = *(const f4*)&x[sbuf[e] * 32 + 4 * q];
          a0 += w0[e] * xv; a1 += w1w[e] * xv; a2 += w2w[e] * xv; a3 += w3w[e] * xv;
        }
        __builtin_amdgcn_wave_barrier();
      }
      if (eg == 0) {
        f4 xv = *(const f4*)&x[n * 32 + 4 * q];
        a0 += wself[0] * xv; a1 += wself[1] * xv; a2 += wself[2] * xv; a3 += wself[3] * xv;
      }
    }

    // reduce across edge-groups (xor 8,16,32)
#pragma unroll
    for (int off = 8; off <= 32; off <<= 1) {
#pragma unroll
      for (int cc = 0; cc < 4; ++cc) {
        a0[cc] += __shfl_xor(a0[cc], off);
        a1[cc] += __shfl_xor(a1[cc], off);
        a2[cc] += __shfl_xor(a2[cc], off);
        a3[cc] += __shfl_xor(a3[cc], off);
      }
    }
    if (eg == 0) {
      *(f4*)&ysh[0 * 32 + 4 * q] = a0;
      *(f4*)&ysh[1 * 32 + 4 * q] = a1;
      *(f4*)&ysh[2 * 32 + 4 * q] = a2;
      *(f4*)&ysh[3 * 32 + 4 * q] = a3;
    }
    __builtin_amdgcn_wave_barrier();

    // matvec1 + ELU (weights from LDS): lane owns 4 out-channels; k halves across lane pairs
    int cl = l & 31, kh = l >> 5;
    int ch = cl * 4, hh = cl >> 3;
    f4 o = {0,0,0,0};
#pragma unroll
    for (int kk = 0; kk < 16; ++kk) {
      int k = kh * 16 + kk;
      float yv = ysh[hh * 32 + k];
      o += yv * *(const f4*)&W1sh[k * 128 + ch];
    }
#pragma unroll
    for (int cc = 0; cc < 4; ++cc) o[cc] += __shfl_xor(o[cc], 32);
    if (kh == 0) {
      o += *(const f4*)&b1sh[ch];
#pragma unroll
      for (int cc = 0; cc < 4; ++cc) o[cc] = elu1(o[cc]);
      *(f4*)&osh[ch] = o;
    }
    __builtin_amdgcn_wave_barrier();

    // matvec2 (weights from LDS): lane owns 4 channels x 16-k group
    int c4 = q * 4;
    f4 p = {0,0,0,0};
#pragma unroll
    for (int kk = 0; kk < 16; ++kk) {
      int k = eg * 16 + kk;
      p += osh[k] * *(const f4*)&W2sh[k * 32 + c4];
    }
#pragma unroll
    for (int off = 8; off <= 32; off <<= 1)
#pragma unroll
      for (int cc = 0; cc < 4; ++cc) p[cc] += __shfl_xor(p[cc], off);

    float ps = 0.0f, pd = 0.0f;
    if (eg == 0) {
      *(f4*)&h2[n * 32 + c4] = p;
      f4 av = *(const f4*)&as2sh[c4];
      f4 dv = *(const f4*)&ad2sh[c4];
      ps = p.x * av.x + p.y * av.y + p.z * av.z + p.w * av.w;
      pd = p.x * dv.x + p.y * dv.y + p.z * dv.z + p.w * dv.w;
    }
#pragma unroll
    for (int off = 1; off <= 4; off <<= 1) {
      ps += __shfl_xor(ps, off);
      pd += __shfl_xor(pd, off);
    }
    if (l == 0) { es2[n] = ps; ed2[n] = pd; }
    __builtin_amdgcn_wave_barrier();
  }
}

// ---------------- agg2: wave-per-node, b128 gather, scalar weight LDS ----------------
__global__ __launch_bounds__(256) void k_agg2(const int* __restrict__ rp, const int* __restrict__ adj,
                                              const float* __restrict__ es, const float* __restrict__ ed,
                                              const float* __restrict__ h, const float* __restrict__ b2,
                                              float* __restrict__ out) {
  __shared__ int sbuf_all[4][66];
  __shared__ float wbuf_all[4][66];
  int wv = threadIdx.x >> 6;
  int l = threadIdx.x & 63;
  int n = blockIdx.x * 4 + wv;
  if (n >= NT) return;
  int* sbuf = sbuf_all[wv];
  float* wbuf = wbuf_all[wv];
  int rs = rp[n], re = rp[n + 1];
  int deg = re - rs;
  float edst = ed[n];
  float vs = lrelu(es[n] + edst);
  int eg = l >> 3, q = l & 7;
  f4 acc = {0,0,0,0};

  if (deg <= 64) {
    float v = -1e30f;
    if (l < deg) {
      int s = adj[rs + l];
      sbuf[l] = s;
      v = lrelu(es[s] + edst);
    }
    float m = v;
#pragma unroll
    for (int off = 1; off <= 32; off <<= 1) m = fmaxf(m, __shfl_xor(m, off));
    m = fmaxf(m, vs);
    float ex = (l < deg) ? __expf(v - m) : 0.0f;
    float d = ex;
#pragma unroll
    for (int off = 1; off <= 32; off <<= 1) d += __shfl_xor(d, off);
    float sv = __expf(vs - m);
    float inv = 1.0f / (d + sv);
    if (l < deg) wbuf[l] = ex * inv;
    if (l == 0) { sbuf[deg] = n; wbuf[deg] = sv * inv; }
    __builtin_amdgcn_wave_barrier();
    for (int e = eg; e <= deg; e += 8) {
      acc += wbuf[e] * *(const f4*)&h[sbuf[e] * 32 + 4 * q];
    }
  } else {
    // generic path (rare)
    float m = -1e30f, den = 0.0f;
    for (int j = rs + l; j < re; j += 64) {
      float v = lrelu(es[adj[j]] + edst);
      if (v > m) { den = den * __expf(m - v) + 1.0f; m = v; }
      else den += __expf(v - m);
    }
#pragma unroll
    for (int off = 1; off <= 32; off <<= 1) {
      float m2 = __shfl_xor(m, off);
      float d2 = __shfl_xor(den, off);
      float mm = fmaxf(m, m2);
      den = den * __expf(m - mm) + d2 * __expf(m2 - mm);
      m = mm;
    }
    float mf = fmaxf(m, vs);
    float dd = den * __expf(m - mf) + __expf(vs - mf);
    float inv = 1.0f / dd;
    float wself = __expf(vs - mf) * inv;
    for (int base = rs; base < re; base += 64) {
      int cnt = min(64, re - base);
      if (l < cnt) {
        int s = adj[base + l];
        sbuf[l] = s;
        wbuf[l] = __expf(lrelu(es[s] + edst) - mf) * inv;
      }
      __builtin_amdgcn_wave_barrier();
      for (int e = eg; e < cnt; e += 8) {
        acc += wbuf[e] * *(const f4*)&h[sbuf[e] * 32 + 4 * q];
      }
      __builtin_amdgcn_wave_barrier();
    }
    if (eg == 0) acc += wself * *(const f4*)&h[n * 32 + 4 * q];
  }

#pragma unroll
  for (int off = 8; off <= 32; off <<= 1)
#pragma unroll
    for (int cc = 0; cc < 4; ++cc) acc[cc] += __shfl_xor(acc[cc], off);
  if (eg == 0) {
    f4 o = acc + *(const f4*)&b2[4 * q];
#pragma unroll
    for (int cc = 0; cc < 4; ++cc) o[cc] = elu1(o[cc]);
    *(f4*)&out[n * 32 + 4 * q] = o;
  }
}

// ---------------- pooling + classifier: one block per graph, zero atomics ----------------
__global__ __launch_bounds__(256) void k_pool2(const float* __restrict__ h, const int* __restrict__ batch,
                                               const float* __restrict__ Wc, const float* __restrict__ bc,
                                               float* __restrict__ out) {
  int g = blockIdx.x;
  int lo = 0, hi = NT;
  while (lo < hi) { int mid = (lo + hi) >> 1; if (batch[mid] < g) lo = mid + 1; else hi = mid; }
  int start = lo;
  hi = NT;
  while (lo < hi) { int mid = (lo + hi) >> 1; if (batch[mid] < g + 1) lo = mid + 1; else hi = mid; }
  int end = lo;

  int t = threadIdx.x, c = t & 31, r = t >> 5;
  float acc = 0.0f;
  for (int n = start + r; n < end; n += 8) acc += h[n * 32 + c];
  __shared__ float sh[256];
  sh[t] = acc;
  __syncthreads();
  if (r == 0) {
    float s = 0.0f;
#pragma unroll
    for (int i = 0; i < 8; ++i) s += sh[i * 32 + c];
    float cnt = (float)(end - start);
    float inv = 1.0f / fmaxf(cnt, 1.0f);
    float v = s * inv * Wc[c];
#pragma unroll
    for (int off = 16; off >= 1; off >>= 1) v += __shfl_xor(v, off);
    if (c == 0) out[g] = v + bc[0];
  }
}

extern "C" void kernel_launch(void* const* d_in, const int* in_sizes, int n_in,
                              void* d_out, int out_size, void* d_ws, size_t ws_size,
                              hipStream_t stream) {
  const float* x = (const float*)d_in[0];
  const int* ei = (const int*)d_in[1];
  const int* src = ei;
  const int* dst = ei + ET;
  const int* batch = (const int*)d_in[2];
  const float* W1 = (const float*)d_in[3];
  const float* asrc1 = (const float*)d_in[4];
  const float* adst1 = (const float*)d_in[5];
  const float* b1 = (const float*)d_in[6];
  const float* W2 = (const float*)d_in[7];
  const float* asrc2 = (const float*)d_in[8];
  const float* adst2 = (const float*)d_in[9];
  const float* b2 = (const float*)d_in[10];
  const float* Wc = (const float*)d_in[11];
  const float* bc = (const float*)d_in[12];
  float* out = (float*)d_out;
  char* ws = (char*)d_ws;

  int* row_ptr = (int*)(ws + 0);          // 400128
  int* cursor = (int*)(ws + 400128);      // 400000
  int* partials = (int*)(ws + 800256);    // 512
  float* AB = (float*)(ws + 800768);      // 1024
  int* adj = (int*)(ws + 801792);         // 6.4MB -> 7201792
  float* es1 = (float*)(ws + 7201792);    // 1.6MB  (16B aligned)
  float* ed1 = (float*)(ws + 8801792);    // 1.6MB  (16B aligned)
  float* es2 = (float*)(ws + 10401792);   // 400KB
  float* ed2 = (float*)(ws + 10801792);   // 400KB
  float* h2 = (float*)(ws + 11201792);    // 12.8MB -> 24001792
  float* h2o = (float*)(ws + 24001792);   // 12.8MB -> 36801792

  hipMemsetAsync(cursor, 0, NT * 4, stream);

  // CSR build (shared by both layers)
  k_count<<<(ET + 255) / 256, 256, 0, stream>>>(dst, cursor);
  k_scan1<<<98, 256, 0, stream>>>(cursor, row_ptr, partials);
  k_scan2<<<1, 64, 0, stream>>>(partials);
  k_scan3<<<(NT + 255) / 256, 256, 0, stream>>>(row_ptr, cursor, partials);
  k_scatter<<<(ET + 255) / 256, 256, 0, stream>>>(src, dst, cursor, adj);

  // layer 1 attention logits (tiny projection, no h1 materialization)
  k_prep<<<1, 256, 0, stream>>>(W1, asrc1, adst1, AB);
  k_att1<<<(NT + 31) / 32, 256, 0, stream>>>(x, AB, es1, ed1);

  // fused: L1 aggregate (input space) + L1 matvec + ELU + L2 GEMM + L2 logits
  k_agg1f<<<(NT + 15) / 16, 256, 0, stream>>>(row_ptr, adj, es1, ed1, x, W1, b1, W2,
                                              asrc2, adst2, h2, es2, ed2);

  // layer 2 aggregation
  k_agg2<<<(NT + 3) / 4, 256, 0, stream>>>(row_ptr, adj, es2, ed2, h2, b2, h2o);

  // pool + classify
  k_pool2<<<GT, 256, 0, stream>>>(h2o, batch, Wc, bc, out);
}

// Round 9
// 390.116 us; speedup vs baseline: 1.3496x; 1.3496x over previous
//
#include <hip/hip_runtime.h>
#include <math.h>

#define NT 100000
#define ET 1600000
#define GT 128

typedef float f4 __attribute__((ext_vector_type(4)));

__device__ __forceinline__ float lrelu(float v) { return v > 0.0f ? v : 0.2f * v; }
__device__ __forceinline__ float elu1(float v) { return v > 0.0f ? v : __expf(v) - 1.0f; }

// ---------------- CSR build ----------------
__global__ void k_count(const int* __restrict__ dst, int* __restrict__ counts) {
  int e = blockIdx.x * 256 + threadIdx.x;
  if (e < ET) atomicAdd(&counts[dst[e]], 1);
}

__global__ __launch_bounds__(256) void k_scan1(const int* __restrict__ counts,
                                               int* __restrict__ scanned,
                                               int* __restrict__ partials) {
  __shared__ int sh[256];
  int t = threadIdx.x;
  int base = blockIdx.x * 1024 + t * 4;
  int v[4];
#pragma unroll
  for (int i = 0; i < 4; ++i) v[i] = (base + i < NT) ? counts[base + i] : 0;
  int tsum = v[0] + v[1] + v[2] + v[3];
  sh[t] = tsum;
  __syncthreads();
  for (int off = 1; off < 256; off <<= 1) {
    int xv = (t >= off) ? sh[t - off] : 0;
    __syncthreads();
    sh[t] += xv;
    __syncthreads();
  }
  int ex = sh[t] - tsum;
#pragma unroll
  for (int i = 0; i < 4; ++i) {
    if (base + i < NT) scanned[base + i] = ex;
    ex += v[i];
  }
  if (t == 255) partials[blockIdx.x] = sh[255];
}

// parallel exclusive scan of the 98 block partials (was single-threaded)
__global__ void k_scan2(int* partials) {
  __shared__ int sh[128];
  int t = threadIdx.x;
  int v = (t < 98) ? partials[t] : 0;
  sh[t] = v;
  __syncthreads();
  for (int off = 1; off < 128; off <<= 1) {
    int xv = (t >= off) ? sh[t - off] : 0;
    __syncthreads();
    sh[t] += xv;
    __syncthreads();
  }
  if (t < 98) partials[t] = sh[t] - v;
}

__global__ void k_scan3(int* __restrict__ rp, int* __restrict__ cursor,
                        const int* __restrict__ partials) {
  int i = blockIdx.x * 256 + threadIdx.x;
  if (i < NT) {
    int v = rp[i] + partials[i >> 10];
    rp[i] = v;
    cursor[i] = v;
    if (i == 0) rp[NT] = ET;
  }
}

__global__ void k_scatter(const int* __restrict__ src, const int* __restrict__ dst,
                          int* __restrict__ cursor, int* __restrict__ adj) {
  int e = blockIdx.x * 256 + threadIdx.x;
  if (e < ET) {
    int pos = atomicAdd(&cursor[dst[e]], 1);
    adj[pos] = src[e];
  }
}

// ---------------- prep: AB[k][j] = sum_c W1[k][h*32+c] * a[h][c]  (j<4: src, j>=4: dst) ----------------
__global__ void k_prep(const float* __restrict__ W1, const float* __restrict__ as1,
                       const float* __restrict__ ad1, float* __restrict__ AB) {
  int t = threadIdx.x;  // 256
  int k = t >> 3, j = t & 7;
  const float* a = (j < 4) ? as1 : ad1;
  int h = j & 3;
  float s = 0.0f;
  for (int c = 0; c < 32; ++c) s += W1[k * 128 + h * 32 + c] * a[h * 32 + c];
  AB[t] = s;  // AB[k*8 + j]
}

// ---------------- att1: es1/ed1 = x @ AB (N x 32 x 8) ----------------
__global__ __launch_bounds__(256) void k_att1(const float* __restrict__ x, const float* __restrict__ AB,
                                              float* __restrict__ es, float* __restrict__ ed) {
  __shared__ float xsh[32 * 33];
  __shared__ float absh[256];
  int t = threadIdx.x;
  int n0 = blockIdx.x * 32;
  absh[t] = AB[t];
  for (int i = t; i < 1024; i += 256) {
    int ln = i >> 5, k = i & 31;
    int node = n0 + ln;
    xsh[ln * 33 + k] = (node < NT) ? x[node * 32 + k] : 0.0f;
  }
  __syncthreads();
  int ln = t >> 3, j = t & 7;
  int node = n0 + ln;
  if (node < NT) {
    float s = 0.0f;
#pragma unroll
    for (int k = 0; k < 32; ++k) s += xsh[ln * 33 + k] * absh[k * 8 + j];
    if (j < 4) es[node * 4 + j] = s;
    else ed[node * 4 + (j - 4)] = s;
  }
}

// ---------------- agg1f: fused L1 aggregate + L1 matvec + ELU + L2 GEMM + L2 logits ----------------
// 8 nodes/block: gather phase = 2 nodes/wave (32 lanes each, no-max softmax);
// matvec phases block-wide (one W1/W2 pass serves 8 nodes).
__global__ __launch_bounds__(256) void k_agg1f(
    const int* __restrict__ rp, const int* __restrict__ adj,
    const float* __restrict__ es, const float* __restrict__ ed,
    const float* __restrict__ x,
    const float* __restrict__ W1, const float* __restrict__ b1,
    const float* __restrict__ W2,
    const float* __restrict__ as2, const float* __restrict__ ad2,
    float* __restrict__ h2, float* __restrict__ es2, float* __restrict__ ed2) {
  __shared__ int sbuf[8][34];
  __shared__ f4 wbufv[8][34];
  __shared__ float ysh[8][132];   // [ns][h*33+k]
  __shared__ float osh[8][132];   // [ns][kg*33+kk]
  int t = threadIdx.x;
  int wv = t >> 6, l = t & 63;
  int g = l >> 5, j = l & 31;
  int ns = wv * 2 + g;
  int n = blockIdx.x * 8 + ns;
  bool valid = (n < NT);
  int nc = valid ? n : NT - 1;
  const f4* es4 = (const f4*)es;
  int rs = rp[nc], re = rp[nc + 1];
  int deg = re - rs;
  f4 edn = ((const f4*)ed)[nc];
  f4 esn = es4[nc];
  float sv[4];
#pragma unroll
  for (int h = 0; h < 4; ++h) sv[h] = __expf(lrelu(esn[h] + edn[h]));
  int eg2 = j >> 3, q = j & 7;
  f4 a0 = {0,0,0,0}, a1 = {0,0,0,0}, a2 = {0,0,0,0}, a3 = {0,0,0,0};

  if (deg <= 32) {
    float ex[4] = {0.0f, 0.0f, 0.0f, 0.0f};
    if (j < deg) {
      int s = adj[rs + j];
      sbuf[ns][j] = s;
      f4 ev = es4[s];
#pragma unroll
      for (int h = 0; h < 4; ++h) ex[h] = __expf(lrelu(ev[h] + edn[h]));
    }
    float d[4] = {ex[0], ex[1], ex[2], ex[3]};
#pragma unroll
    for (int off = 1; off <= 16; off <<= 1)
#pragma unroll
      for (int h = 0; h < 4; ++h) d[h] += __shfl_xor(d[h], off);
    float inv[4];
#pragma unroll
    for (int h = 0; h < 4; ++h) inv[h] = 1.0f / (d[h] + sv[h]);
    if (j < deg) {
      f4 w4;
#pragma unroll
      for (int h = 0; h < 4; ++h) w4[h] = ex[h] * inv[h];
      wbufv[ns][j] = w4;
    }
    if (j == 0) {
      sbuf[ns][deg] = nc;
      f4 w4;
#pragma unroll
      for (int h = 0; h < 4; ++h) w4[h] = sv[h] * inv[h];
      wbufv[ns][deg] = w4;
    }
    __builtin_amdgcn_wave_barrier();
    for (int e = eg2; e <= deg; e += 4) {
      f4 xv = *(const f4*)&x[sbuf[ns][e] * 32 + 4 * q];
      f4 w4 = wbufv[ns][e];
      a0 += w4.x * xv; a1 += w4.y * xv; a2 += w4.z * xv; a3 += w4.w * xv;
    }
  } else {
    // generic (deg > 32, rare): no-max two-pass chunked
    float d[4] = {0.0f, 0.0f, 0.0f, 0.0f};
    for (int jj = rs + j; jj < re; jj += 32) {
      f4 ev = es4[adj[jj]];
#pragma unroll
      for (int h = 0; h < 4; ++h) d[h] += __expf(lrelu(ev[h] + edn[h]));
    }
#pragma unroll
    for (int off = 1; off <= 16; off <<= 1)
#pragma unroll
      for (int h = 0; h < 4; ++h) d[h] += __shfl_xor(d[h], off);
    float inv[4];
#pragma unroll
    for (int h = 0; h < 4; ++h) inv[h] = 1.0f / (d[h] + sv[h]);
    for (int base = rs; base < re; base += 32) {
      int cnt = min(32, re - base);
      if (j < cnt) {
        int s = adj[base + j];
        sbuf[ns][j] = s;
        f4 ev = es4[s];
        f4 w4;
#pragma unroll
        for (int h = 0; h < 4; ++h) w4[h] = __expf(lrelu(ev[h] + edn[h])) * inv[h];
        wbufv[ns][j] = w4;
      }
      __builtin_amdgcn_wave_barrier();
      for (int e = eg2; e < cnt; e += 4) {
        f4 xv = *(const f4*)&x[sbuf[ns][e] * 32 + 4 * q];
        f4 w4 = wbufv[ns][e];
        a0 += w4.x * xv; a1 += w4.y * xv; a2 += w4.z * xv; a3 += w4.w * xv;
      }
      __builtin_amdgcn_wave_barrier();
    }
    if (eg2 == 0) {
      f4 xv = *(const f4*)&x[nc * 32 + 4 * q];
      a0 += sv[0] * inv[0] * xv; a1 += sv[1] * inv[1] * xv;
      a2 += sv[2] * inv[2] * xv; a3 += sv[3] * inv[3] * xv;
    }
  }

  // reduce across 4 edge-groups (xor 8, 16 stay within each 32-half)
#pragma unroll
  for (int off = 8; off <= 16; off <<= 1) {
#pragma unroll
    for (int cc = 0; cc < 4; ++cc) {
      a0[cc] += __shfl_xor(a0[cc], off);
      a1[cc] += __shfl_xor(a1[cc], off);
      a2[cc] += __shfl_xor(a2[cc], off);
      a3[cc] += __shfl_xor(a3[cc], off);
    }
  }
  if (eg2 == 0) {
    *(f4*)&ysh[ns][0 * 33 + 4 * q] = a0;
    *(f4*)&ysh[ns][1 * 33 + 4 * q] = a1;
    *(f4*)&ysh[ns][2 * 33 + 4 * q] = a2;
    *(f4*)&ysh[ns][3 * 33 + 4 * q] = a3;
  }
  __syncthreads();

  // matvec1 + ELU, block-wide: thread t -> node ns2=t>>5, channels ch..ch+3
  {
    int ns2 = t >> 5, j2 = t & 31;
    int ch = j2 * 4, hh = j2 >> 3;
    f4 o = {0,0,0,0};
#pragma unroll
    for (int k = 0; k < 32; ++k) {
      o += ysh[ns2][hh * 33 + k] * *(const f4*)&W1[k * 128 + ch];
    }
    o += *(const f4*)&b1[ch];
#pragma unroll
    for (int cc = 0; cc < 4; ++cc) o[cc] = elu1(o[cc]);
    *(f4*)&osh[ns2][(ch >> 5) * 33 + (ch & 31)] = o;
  }
  __syncthreads();

  // matvec2, block-wide: thread t -> node ns2, k-group kg, channels c4..c4+3
  {
    int ns2 = t >> 5, j2 = t & 31;
    int kg = j2 >> 3, c4 = (j2 & 7) * 4;
    int n2 = blockIdx.x * 8 + ns2;
    bool v2 = (n2 < NT);
    f4 p = {0,0,0,0};
#pragma unroll
    for (int kk = 0; kk < 32; ++kk) {
      p += osh[ns2][kg * 33 + kk] * *(const f4*)&W2[(kg * 32 + kk) * 32 + c4];
    }
#pragma unroll
    for (int off = 8; off <= 16; off <<= 1)
#pragma unroll
      for (int cc = 0; cc < 4; ++cc) p[cc] += __shfl_xor(p[cc], off);
    if (kg == 0) {
      if (v2) *(f4*)&h2[n2 * 32 + c4] = p;
      f4 av = *(const f4*)&as2[c4];
      f4 dv = *(const f4*)&ad2[c4];
      float ps = p.x * av.x + p.y * av.y + p.z * av.z + p.w * av.w;
      float pd = p.x * dv.x + p.y * dv.y + p.z * dv.z + p.w * dv.w;
#pragma unroll
      for (int off = 1; off <= 4; off <<= 1) {
        ps += __shfl_xor(ps, off);
        pd += __shfl_xor(pd, off);
      }
      if ((j2 & 7) == 0 && v2) { es2[n2] = ps; ed2[n2] = pd; }
    }
  }
}

// ---------------- agg2: 2 nodes/wave, no-max softmax, fused h2o.Wc -> z ----------------
__global__ __launch_bounds__(256) void k_agg2(const int* __restrict__ rp, const int* __restrict__ adj,
                                              const float* __restrict__ es, const float* __restrict__ ed,
                                              const float* __restrict__ h, const float* __restrict__ b2,
                                              const float* __restrict__ Wc, float* __restrict__ z) {
  __shared__ int sbuf[8][34];
  __shared__ float wsh[8][34];
  int t = threadIdx.x;
  int wv = t >> 6, l = t & 63;
  int g = l >> 5, j = l & 31;
  int ns = wv * 2 + g;
  int n = blockIdx.x * 8 + ns;
  if (n >= NT) return;
  int rs = rp[n], re = rp[n + 1];
  int deg = re - rs;
  float edn = ed[n];
  float sv = __expf(lrelu(es[n] + edn));
  int eg2 = j >> 3, q = j & 7;
  f4 acc = {0,0,0,0};

  if (deg <= 32) {
    float ex = 0.0f;
    if (j < deg) {
      int s = adj[rs + j];
      sbuf[ns][j] = s;
      ex = __expf(lrelu(es[s] + edn));
    }
    float d = ex;
#pragma unroll
    for (int off = 1; off <= 16; off <<= 1) d += __shfl_xor(d, off);
    float inv = 1.0f / (d + sv);
    if (j < deg) wsh[ns][j] = ex * inv;
    if (j == 0) { sbuf[ns][deg] = n; wsh[ns][deg] = sv * inv; }
    __builtin_amdgcn_wave_barrier();
    for (int e = eg2; e <= deg; e += 4) {
      acc += wsh[ns][e] * *(const f4*)&h[sbuf[ns][e] * 32 + 4 * q];
    }
  } else {
    // generic (rare): no-max two-pass chunked
    float d = 0.0f;
    for (int jj = rs + j; jj < re; jj += 32) d += __expf(lrelu(es[adj[jj]] + edn));
#pragma unroll
    for (int off = 1; off <= 16; off <<= 1) d += __shfl_xor(d, off);
    float inv = 1.0f / (d + sv);
    for (int base = rs; base < re; base += 32) {
      int cnt = min(32, re - base);
      if (j < cnt) {
        int s = adj[base + j];
        sbuf[ns][j] = s;
        wsh[ns][j] = __expf(lrelu(es[s] + edn)) * inv;
      }
      __builtin_amdgcn_wave_barrier();
      for (int e = eg2; e < cnt; e += 4) {
        acc += wsh[ns][e] * *(const f4*)&h[sbuf[ns][e] * 32 + 4 * q];
      }
      __builtin_amdgcn_wave_barrier();
    }
    if (eg2 == 0) acc += sv * inv * *(const f4*)&h[n * 32 + 4 * q];
  }

#pragma unroll
  for (int off = 8; off <= 16; off <<= 1)
#pragma unroll
    for (int cc = 0; cc < 4; ++cc) acc[cc] += __shfl_xor(acc[cc], off);
  if (eg2 == 0) {
    f4 o = acc + *(const f4*)&b2[4 * q];
#pragma unroll
    for (int cc = 0; cc < 4; ++cc) o[cc] = elu1(o[cc]);
    f4 wc = *(const f4*)&Wc[4 * q];
    float zz = o.x * wc.x + o.y * wc.y + o.z * wc.z + o.w * wc.w;
#pragma unroll
    for (int off = 1; off <= 4; off <<= 1) zz += __shfl_xor(zz, off);
    if (q == 0) z[n] = zz;
  }
}

// ---------------- pooling: one block per graph, sums scalar z ----------------
__global__ __launch_bounds__(256) void k_poolz(const float* __restrict__ z, const int* __restrict__ batch,
                                               const float* __restrict__ bc, float* __restrict__ out) {
  int g = blockIdx.x;
  int lo = 0, hi = NT;
  while (lo < hi) { int mid = (lo + hi) >> 1; if (batch[mid] < g) lo = mid + 1; else hi = mid; }
  int start = lo;
  hi = NT;
  while (lo < hi) { int mid = (lo + hi) >> 1; if (batch[mid] < g + 1) lo = mid + 1; else hi = mid; }
  int end = lo;

  int t = threadIdx.x;
  float s = 0.0f;
  for (int n = start + t; n < end; n += 256) s += z[n];
#pragma unroll
  for (int off = 1; off <= 32; off <<= 1) s += __shfl_xor(s, off);
  __shared__ float sh[4];
  if ((t & 63) == 0) sh[t >> 6] = s;
  __syncthreads();
  if (t == 0) {
    float tot = sh[0] + sh[1] + sh[2] + sh[3];
    float cnt = (float)(end - start);
    out[g] = tot / fmaxf(cnt, 1.0f) + bc[0];
  }
}

extern "C" void kernel_launch(void* const* d_in, const int* in_sizes, int n_in,
                              void* d_out, int out_size, void* d_ws, size_t ws_size,
                              hipStream_t stream) {
  const float* x = (const float*)d_in[0];
  const int* ei = (const int*)d_in[1];
  const int* src = ei;
  const int* dst = ei + ET;
  const int* batch = (const int*)d_in[2];
  const float* W1 = (const float*)d_in[3];
  const float* asrc1 = (const float*)d_in[4];
  const float* adst1 = (const float*)d_in[5];
  const float* b1 = (const float*)d_in[6];
  const float* W2 = (const float*)d_in[7];
  const float* asrc2 = (const float*)d_in[8];
  const float* adst2 = (const float*)d_in[9];
  const float* b2 = (const float*)d_in[10];
  const float* Wc = (const float*)d_in[11];
  const float* bc = (const float*)d_in[12];
  float* out = (float*)d_out;
  char* ws = (char*)d_ws;

  int* row_ptr = (int*)(ws + 0);          // 400128
  int* cursor = (int*)(ws + 400128);      // 400000
  int* partials = (int*)(ws + 800256);    // 512
  float* AB = (float*)(ws + 800768);      // 1024
  int* adj = (int*)(ws + 801792);         // 6.4MB -> 7201792
  float* es1 = (float*)(ws + 7201792);    // 1.6MB  (16B aligned)
  float* ed1 = (float*)(ws + 8801792);    // 1.6MB  (16B aligned)
  float* es2 = (float*)(ws + 10401792);   // 400KB
  float* ed2 = (float*)(ws + 10801792);   // 400KB
  float* h2 = (float*)(ws + 11201792);    // 12.8MB -> 24001792
  float* z = (float*)(ws + 24001792);     // 400KB

  hipMemsetAsync(cursor, 0, NT * 4, stream);

  // CSR build (shared by both layers)
  k_count<<<(ET + 255) / 256, 256, 0, stream>>>(dst, cursor);
  k_scan1<<<98, 256, 0, stream>>>(cursor, row_ptr, partials);
  k_scan2<<<1, 128, 0, stream>>>(partials);
  k_scan3<<<(NT + 255) / 256, 256, 0, stream>>>(row_ptr, cursor, partials);
  k_scatter<<<(ET + 255) / 256, 256, 0, stream>>>(src, dst, cursor, adj);

  // layer 1 attention logits (tiny projection, no h1 materialization)
  k_prep<<<1, 256, 0, stream>>>(W1, asrc1, adst1, AB);
  k_att1<<<(NT + 31) / 32, 256, 0, stream>>>(x, AB, es1, ed1);

  // fused: L1 aggregate (input space) + L1 matvec + ELU + L2 GEMM + L2 logits
  k_agg1f<<<(NT + 7) / 8, 256, 0, stream>>>(row_ptr, adj, es1, ed1, x, W1, b1, W2,
                                            asrc2, adst2, h2, es2, ed2);

  // layer 2 aggregation + ELU + classifier dot (z per node)
  k_agg2<<<(NT + 7) / 8, 256, 0, stream>>>(row_ptr, adj, es2, ed2, h2, b2, Wc, z);

  // pool + bias
  k_poolz<<<GT, 256, 0, stream>>>(z, batch, bc, out);
}

// Round 10
// 222.199 us; speedup vs baseline: 2.3696x; 1.7557x over previous
//
#include <hip/hip_runtime.h>
#include <math.h>

#define NT 100000
#define ET 1600000
#define GT 128
#define NBK 391      // dst>>8 buckets (256 nodes each)
#define BSH 8
#define NBLK_A 256   // blocks in hist/bucketize passes
#define CHUNK_A 6250 // ET / NBLK_A

typedef float f4 __attribute__((ext_vector_type(4)));

__device__ __forceinline__ float lrelu(float v) { return v > 0.0f ? v : 0.2f * v; }
__device__ __forceinline__ float elu1(float v) { return v > 0.0f ? v : __expf(v) - 1.0f; }

// ---------------- CSR build: bucketed two-level, no global atomics ----------------
__global__ __launch_bounds__(256) void k_histA(const int* __restrict__ dst, int* __restrict__ histA) {
  __shared__ int histL[NBK];
  int t = threadIdx.x, blk = blockIdx.x;
  for (int i = t; i < NBK; i += 256) histL[i] = 0;
  __syncthreads();
  int e0 = blk * CHUNK_A, e1 = min(ET, e0 + CHUNK_A);
  for (int e = e0 + t; e < e1; e += 256) atomicAdd(&histL[dst[e] >> BSH], 1);
  __syncthreads();
  for (int i = t; i < NBK; i += 256) histA[i * NBLK_A + blk] = histL[i];
}

// per-bucket exclusive scan over the NBLK_A block-counts
__global__ __launch_bounds__(256) void k_scanB(int* __restrict__ histA, int* __restrict__ btot) {
  __shared__ int sh[256];
  int b = blockIdx.x, t = threadIdx.x;
  int v = histA[b * NBLK_A + t];
  sh[t] = v;
  __syncthreads();
  for (int off = 1; off < 256; off <<= 1) {
    int xv = (t >= off) ? sh[t - off] : 0;
    __syncthreads();
    sh[t] += xv;
    __syncthreads();
  }
  histA[b * NBLK_A + t] = sh[t] - v;
  if (t == 255) btot[b] = sh[255];
}

// exclusive scan of bucket totals
__global__ __launch_bounds__(512) void k_scanC(const int* __restrict__ btot, int* __restrict__ bbase) {
  __shared__ int sh[512];
  int t = threadIdx.x;
  int v = (t < NBK) ? btot[t] : 0;
  sh[t] = v;
  __syncthreads();
  for (int off = 1; off < 512; off <<= 1) {
    int xv = (t >= off) ? sh[t - off] : 0;
    __syncthreads();
    sh[t] += xv;
    __syncthreads();
  }
  if (t < NBK) bbase[t] = sh[t] - v;
  if (t == 0) bbase[NBK] = ET;
}

// bucketize edges into ebuf (LDS cursors; writes cluster per bucket region)
__global__ __launch_bounds__(256) void k_buck(const int* __restrict__ src, const int* __restrict__ dst,
                                              const int* __restrict__ histA, const int* __restrict__ bbase,
                                              int2* __restrict__ ebuf) {
  __shared__ int cur[NBK];
  int t = threadIdx.x, blk = blockIdx.x;
  for (int i = t; i < NBK; i += 256) cur[i] = histA[i * NBLK_A + blk] + bbase[i];
  __syncthreads();
  int e0 = blk * CHUNK_A, e1 = min(ET, e0 + CHUNK_A);
  for (int e = e0 + t; e < e1; e += 256) {
    int s = src[e], d = dst[e];
    int pos = atomicAdd(&cur[d >> BSH], 1);
    ebuf[pos] = make_int2(s, d);
  }
}

// per-bucket fine pass: count/scan/scatter in LDS, emit row_ptr + adj
__global__ __launch_bounds__(256) void k_fine(const int2* __restrict__ ebuf, const int* __restrict__ bbase,
                                              int* __restrict__ rp, int* __restrict__ adj) {
  __shared__ int cnt[256];
  __shared__ int sh[256];
  __shared__ int cur[256];
  int b = blockIdx.x, t = threadIdx.x;
  int eb0 = bbase[b], eb1 = bbase[b + 1];
  cnt[t] = 0;
  __syncthreads();
  for (int e = eb0 + t; e < eb1; e += 256) atomicAdd(&cnt[ebuf[e].y & 255], 1);
  __syncthreads();
  int v = cnt[t];
  sh[t] = v;
  __syncthreads();
  for (int off = 1; off < 256; off <<= 1) {
    int xv = (t >= off) ? sh[t - off] : 0;
    __syncthreads();
    sh[t] += xv;
    __syncthreads();
  }
  int start = eb0 + sh[t] - v;
  cur[t] = start;
  int node = (b << BSH) + t;
  if (node < NT) rp[node] = start;
  if (node == NT - 1) rp[NT] = ET;
  __syncthreads();
  for (int e = eb0 + t; e < eb1; e += 256) {
    int2 p = ebuf[e];
    int pos = atomicAdd(&cur[p.y & 255], 1);
    adj[pos] = p.x;
  }
}

// ---------------- prep: AB[k][j] = sum_c W1[k][h*32+c] * a[h][c]  (j<4: src, j>=4: dst) ----------------
__global__ void k_prep(const float* __restrict__ W1, const float* __restrict__ as1,
                       const float* __restrict__ ad1, float* __restrict__ AB) {
  int t = threadIdx.x;  // 256
  int k = t >> 3, j = t & 7;
  const float* a = (j < 4) ? as1 : ad1;
  int h = j & 3;
  float s = 0.0f;
  for (int c = 0; c < 32; ++c) s += W1[k * 128 + h * 32 + c] * a[h * 32 + c];
  AB[t] = s;  // AB[k*8 + j]
}

// ---------------- att1: es1/ed1 = x @ AB (N x 32 x 8) ----------------
__global__ __launch_bounds__(256) void k_att1(const float* __restrict__ x, const float* __restrict__ AB,
                                              float* __restrict__ es, float* __restrict__ ed) {
  __shared__ float xsh[32 * 33];
  __shared__ float absh[256];
  int t = threadIdx.x;
  int n0 = blockIdx.x * 32;
  absh[t] = AB[t];
  for (int i = t; i < 1024; i += 256) {
    int ln = i >> 5, k = i & 31;
    int node = n0 + ln;
    xsh[ln * 33 + k] = (node < NT) ? x[node * 32 + k] : 0.0f;
  }
  __syncthreads();
  int ln = t >> 3, j = t & 7;
  int node = n0 + ln;
  if (node < NT) {
    float s = 0.0f;
#pragma unroll
    for (int k = 0; k < 32; ++k) s += xsh[ln * 33 + k] * absh[k * 8 + j];
    if (j < 4) es[node * 4 + j] = s;
    else ed[node * 4 + (j - 4)] = s;
  }
}

// ---------------- agg1f: fused L1 aggregate + L1 matvec + ELU + L2 GEMM + L2 logits ----------------
__global__ __launch_bounds__(256) void k_agg1f(
    const int* __restrict__ rp, const int* __restrict__ adj,
    const float* __restrict__ es, const float* __restrict__ ed,
    const float* __restrict__ x,
    const float* __restrict__ W1, const float* __restrict__ b1,
    const float* __restrict__ W2,
    const float* __restrict__ as2, const float* __restrict__ ad2,
    float* __restrict__ h2, float* __restrict__ es2, float* __restrict__ ed2) {
  __shared__ int sbuf[8][34];
  __shared__ f4 wbufv[8][34];
  __shared__ float ysh[8][132];   // [ns][h*33+k]
  __shared__ float osh[8][132];   // [ns][kg*33+kk]
  int t = threadIdx.x;
  int wv = t >> 6, l = t & 63;
  int g = l >> 5, j = l & 31;
  int ns = wv * 2 + g;
  int n = blockIdx.x * 8 + ns;
  bool valid = (n < NT);
  int nc = valid ? n : NT - 1;
  const f4* es4 = (const f4*)es;
  int rs = rp[nc], re = rp[nc + 1];
  int deg = re - rs;
  f4 edn = ((const f4*)ed)[nc];
  f4 esn = es4[nc];
  float sv[4];
#pragma unroll
  for (int h = 0; h < 4; ++h) sv[h] = __expf(lrelu(esn[h] + edn[h]));
  int eg2 = j >> 3, q = j & 7;
  f4 a0 = {0,0,0,0}, a1 = {0,0,0,0}, a2 = {0,0,0,0}, a3 = {0,0,0,0};

  if (deg <= 32) {
    float ex[4] = {0.0f, 0.0f, 0.0f, 0.0f};
    if (j < deg) {
      int s = adj[rs + j];
      sbuf[ns][j] = s;
      f4 ev = es4[s];
#pragma unroll
      for (int h = 0; h < 4; ++h) ex[h] = __expf(lrelu(ev[h] + edn[h]));
    }
    float d[4] = {ex[0], ex[1], ex[2], ex[3]};
#pragma unroll
    for (int off = 1; off <= 16; off <<= 1)
#pragma unroll
      for (int h = 0; h < 4; ++h) d[h] += __shfl_xor(d[h], off);
    float inv[4];
#pragma unroll
    for (int h = 0; h < 4; ++h) inv[h] = 1.0f / (d[h] + sv[h]);
    if (j < deg) {
      f4 w4;
#pragma unroll
      for (int h = 0; h < 4; ++h) w4[h] = ex[h] * inv[h];
      wbufv[ns][j] = w4;
    }
    if (j == 0) {
      sbuf[ns][deg] = nc;
      f4 w4;
#pragma unroll
      for (int h = 0; h < 4; ++h) w4[h] = sv[h] * inv[h];
      wbufv[ns][deg] = w4;
    }
    __builtin_amdgcn_wave_barrier();
    for (int e = eg2; e <= deg; e += 4) {
      f4 xv = *(const f4*)&x[sbuf[ns][e] * 32 + 4 * q];
      f4 w4 = wbufv[ns][e];
      a0 += w4.x * xv; a1 += w4.y * xv; a2 += w4.z * xv; a3 += w4.w * xv;
    }
  } else {
    // generic (deg > 32, rare): no-max two-pass chunked
    float d[4] = {0.0f, 0.0f, 0.0f, 0.0f};
    for (int jj = rs + j; jj < re; jj += 32) {
      f4 ev = es4[adj[jj]];
#pragma unroll
      for (int h = 0; h < 4; ++h) d[h] += __expf(lrelu(ev[h] + edn[h]));
    }
#pragma unroll
    for (int off = 1; off <= 16; off <<= 1)
#pragma unroll
      for (int h = 0; h < 4; ++h) d[h] += __shfl_xor(d[h], off);
    float inv[4];
#pragma unroll
    for (int h = 0; h < 4; ++h) inv[h] = 1.0f / (d[h] + sv[h]);
    for (int base = rs; base < re; base += 32) {
      int cnt = min(32, re - base);
      if (j < cnt) {
        int s = adj[base + j];
        sbuf[ns][j] = s;
        f4 ev = es4[s];
        f4 w4;
#pragma unroll
        for (int h = 0; h < 4; ++h) w4[h] = __expf(lrelu(ev[h] + edn[h])) * inv[h];
        wbufv[ns][j] = w4;
      }
      __builtin_amdgcn_wave_barrier();
      for (int e = eg2; e < cnt; e += 4) {
        f4 xv = *(const f4*)&x[sbuf[ns][e] * 32 + 4 * q];
        f4 w4 = wbufv[ns][e];
        a0 += w4.x * xv; a1 += w4.y * xv; a2 += w4.z * xv; a3 += w4.w * xv;
      }
      __builtin_amdgcn_wave_barrier();
    }
    if (eg2 == 0) {
      f4 xv = *(const f4*)&x[nc * 32 + 4 * q];
      a0 += sv[0] * inv[0] * xv; a1 += sv[1] * inv[1] * xv;
      a2 += sv[2] * inv[2] * xv; a3 += sv[3] * inv[3] * xv;
    }
  }

  // reduce across 4 edge-groups (xor 8, 16 stay within each 32-half)
#pragma unroll
  for (int off = 8; off <= 16; off <<= 1) {
#pragma unroll
    for (int cc = 0; cc < 4; ++cc) {
      a0[cc] += __shfl_xor(a0[cc], off);
      a1[cc] += __shfl_xor(a1[cc], off);
      a2[cc] += __shfl_xor(a2[cc], off);
      a3[cc] += __shfl_xor(a3[cc], off);
    }
  }
  if (eg2 == 0) {
    *(f4*)&ysh[ns][0 * 33 + 4 * q] = a0;
    *(f4*)&ysh[ns][1 * 33 + 4 * q] = a1;
    *(f4*)&ysh[ns][2 * 33 + 4 * q] = a2;
    *(f4*)&ysh[ns][3 * 33 + 4 * q] = a3;
  }
  __syncthreads();

  // matvec1 + ELU, block-wide: thread t -> node ns2=t>>5, channels ch..ch+3
  {
    int ns2 = t >> 5, j2 = t & 31;
    int ch = j2 * 4, hh = j2 >> 3;
    f4 o = {0,0,0,0};
#pragma unroll
    for (int k = 0; k < 32; ++k) {
      o += ysh[ns2][hh * 33 + k] * *(const f4*)&W1[k * 128 + ch];
    }
    o += *(const f4*)&b1[ch];
#pragma unroll
    for (int cc = 0; cc < 4; ++cc) o[cc] = elu1(o[cc]);
    *(f4*)&osh[ns2][(ch >> 5) * 33 + (ch & 31)] = o;
  }
  __syncthreads();

  // matvec2, block-wide: thread t -> node ns2, k-group kg, channels c4..c4+3
  {
    int ns2 = t >> 5, j2 = t & 31;
    int kg = j2 >> 3, c4 = (j2 & 7) * 4;
    int n2 = blockIdx.x * 8 + ns2;
    bool v2 = (n2 < NT);
    f4 p = {0,0,0,0};
#pragma unroll
    for (int kk = 0; kk < 32; ++kk) {
      p += osh[ns2][kg * 33 + kk] * *(const f4*)&W2[(kg * 32 + kk) * 32 + c4];
    }
#pragma unroll
    for (int off = 8; off <= 16; off <<= 1)
#pragma unroll
      for (int cc = 0; cc < 4; ++cc) p[cc] += __shfl_xor(p[cc], off);
    if (kg == 0) {
      if (v2) *(f4*)&h2[n2 * 32 + c4] = p;
      f4 av = *(const f4*)&as2[c4];
      f4 dv = *(const f4*)&ad2[c4];
      float ps = p.x * av.x + p.y * av.y + p.z * av.z + p.w * av.w;
      float pd = p.x * dv.x + p.y * dv.y + p.z * dv.z + p.w * dv.w;
#pragma unroll
      for (int off = 1; off <= 4; off <<= 1) {
        ps += __shfl_xor(ps, off);
        pd += __shfl_xor(pd, off);
      }
      if ((j2 & 7) == 0 && v2) { es2[n2] = ps; ed2[n2] = pd; }
    }
  }
}

// ---------------- agg2: 2 nodes/wave, no-max softmax, fused h2o.Wc -> z ----------------
__global__ __launch_bounds__(256) void k_agg2(const int* __restrict__ rp, const int* __restrict__ adj,
                                              const float* __restrict__ es, const float* __restrict__ ed,
                                              const float* __restrict__ h, const float* __restrict__ b2,
                                              const float* __restrict__ Wc, float* __restrict__ z) {
  __shared__ int sbuf[8][34];
  __shared__ float wsh[8][34];
  int t = threadIdx.x;
  int wv = t >> 6, l = t & 63;
  int g = l >> 5, j = l & 31;
  int ns = wv * 2 + g;
  int n = blockIdx.x * 8 + ns;
  if (n >= NT) return;
  int rs = rp[n], re = rp[n + 1];
  int deg = re - rs;
  float edn = ed[n];
  float sv = __expf(lrelu(es[n] + edn));
  int eg2 = j >> 3, q = j & 7;
  f4 acc = {0,0,0,0};

  if (deg <= 32) {
    float ex = 0.0f;
    if (j < deg) {
      int s = adj[rs + j];
      sbuf[ns][j] = s;
      ex = __expf(lrelu(es[s] + edn));
    }
    float d = ex;
#pragma unroll
    for (int off = 1; off <= 16; off <<= 1) d += __shfl_xor(d, off);
    float inv = 1.0f / (d + sv);
    if (j < deg) wsh[ns][j] = ex * inv;
    if (j == 0) { sbuf[ns][deg] = n; wsh[ns][deg] = sv * inv; }
    __builtin_amdgcn_wave_barrier();
    for (int e = eg2; e <= deg; e += 4) {
      acc += wsh[ns][e] * *(const f4*)&h[sbuf[ns][e] * 32 + 4 * q];
    }
  } else {
    // generic (rare): no-max two-pass chunked
    float d = 0.0f;
    for (int jj = rs + j; jj < re; jj += 32) d += __expf(lrelu(es[adj[jj]] + edn));
#pragma unroll
    for (int off = 1; off <= 16; off <<= 1) d += __shfl_xor(d, off);
    float inv = 1.0f / (d + sv);
    for (int base = rs; base < re; base += 32) {
      int cnt = min(32, re - base);
      if (j < cnt) {
        int s = adj[base + j];
        sbuf[ns][j] = s;
        wsh[ns][j] = __expf(lrelu(es[s] + edn)) * inv;
      }
      __builtin_amdgcn_wave_barrier();
      for (int e = eg2; e < cnt; e += 4) {
        acc += wsh[ns][e] * *(const f4*)&h[sbuf[ns][e] * 32 + 4 * q];
      }
      __builtin_amdgcn_wave_barrier();
    }
    if (eg2 == 0) acc += sv * inv * *(const f4*)&h[n * 32 + 4 * q];
  }

#pragma unroll
  for (int off = 8; off <= 16; off <<= 1)
#pragma unroll
    for (int cc = 0; cc < 4; ++cc) acc[cc] += __shfl_xor(acc[cc], off);
  if (eg2 == 0) {
    f4 o = acc + *(const f4*)&b2[4 * q];
#pragma unroll
    for (int cc = 0; cc < 4; ++cc) o[cc] = elu1(o[cc]);
    f4 wc = *(const f4*)&Wc[4 * q];
    float zz = o.x * wc.x + o.y * wc.y + o.z * wc.z + o.w * wc.w;
#pragma unroll
    for (int off = 1; off <= 4; off <<= 1) zz += __shfl_xor(zz, off);
    if (q == 0) z[n] = zz;
  }
}

// ---------------- pooling: one block per graph, sums scalar z ----------------
__global__ __launch_bounds__(256) void k_poolz(const float* __restrict__ z, const int* __restrict__ batch,
                                               const float* __restrict__ bc, float* __restrict__ out) {
  int g = blockIdx.x;
  int lo = 0, hi = NT;
  while (lo < hi) { int mid = (lo + hi) >> 1; if (batch[mid] < g) lo = mid + 1; else hi = mid; }
  int start = lo;
  hi = NT;
  while (lo < hi) { int mid = (lo + hi) >> 1; if (batch[mid] < g + 1) lo = mid + 1; else hi = mid; }
  int end = lo;

  int t = threadIdx.x;
  float s = 0.0f;
  for (int n = start + t; n < end; n += 256) s += z[n];
#pragma unroll
  for (int off = 1; off <= 32; off <<= 1) s += __shfl_xor(s, off);
  __shared__ float sh[4];
  if ((t & 63) == 0) sh[t >> 6] = s;
  __syncthreads();
  if (t == 0) {
    float tot = sh[0] + sh[1] + sh[2] + sh[3];
    float cnt = (float)(end - start);
    out[g] = tot / fmaxf(cnt, 1.0f) + bc[0];
  }
}

extern "C" void kernel_launch(void* const* d_in, const int* in_sizes, int n_in,
                              void* d_out, int out_size, void* d_ws, size_t ws_size,
                              hipStream_t stream) {
  const float* x = (const float*)d_in[0];
  const int* ei = (const int*)d_in[1];
  const int* src = ei;
  const int* dst = ei + ET;
  const int* batch = (const int*)d_in[2];
  const float* W1 = (const float*)d_in[3];
  const float* asrc1 = (const float*)d_in[4];
  const float* adst1 = (const float*)d_in[5];
  const float* b1 = (const float*)d_in[6];
  const float* W2 = (const float*)d_in[7];
  const float* asrc2 = (const float*)d_in[8];
  const float* adst2 = (const float*)d_in[9];
  const float* b2 = (const float*)d_in[10];
  const float* Wc = (const float*)d_in[11];
  const float* bc = (const float*)d_in[12];
  float* out = (float*)d_out;
  char* ws = (char*)d_ws;

  int* row_ptr = (int*)(ws + 0);          // 400004 -> pad 400128
  int* histA = (int*)(ws + 400128);       // 391*256*4 = 400384 -> 800512
  int* btot = (int*)(ws + 800512);        // 1564 -> pad 802112
  int* bbase = (int*)(ws + 802112);       // 1568 -> pad 803712
  float* AB = (float*)(ws + 803712);      // 1024 -> 804736
  int2* ebuf = (int2*)(ws + 804736);      // 12.8MB -> 13604736
  int* adj = (int*)(ws + 13604736);       // 6.4MB -> 20004736
  float* es1 = (float*)(ws + 20004736);   // 1.6MB (16B aligned)
  float* ed1 = (float*)(ws + 21604736);   // 1.6MB
  float* es2 = (float*)(ws + 23204736);   // 400KB
  float* ed2 = (float*)(ws + 23604736);   // 400KB
  float* h2 = (float*)(ws + 24004736);    // 12.8MB -> 36804736
  float* z = (float*)(ws + 36804736);     // 400KB

  // CSR build (bucketed, no global atomics, no memset needed)
  k_histA<<<NBLK_A, 256, 0, stream>>>(dst, histA);
  k_scanB<<<NBK, 256, 0, stream>>>(histA, btot);
  k_scanC<<<1, 512, 0, stream>>>(btot, bbase);
  k_buck<<<NBLK_A, 256, 0, stream>>>(src, dst, histA, bbase, ebuf);
  k_fine<<<NBK, 256, 0, stream>>>(ebuf, bbase, row_ptr, adj);

  // layer 1 attention logits (tiny projection, no h1 materialization)
  k_prep<<<1, 256, 0, stream>>>(W1, asrc1, adst1, AB);
  k_att1<<<(NT + 31) / 32, 256, 0, stream>>>(x, AB, es1, ed1);

  // fused: L1 aggregate (input space) + L1 matvec + ELU + L2 GEMM + L2 logits
  k_agg1f<<<(NT + 7) / 8, 256, 0, stream>>>(row_ptr, adj, es1, ed1, x, W1, b1, W2,
                                            asrc2, adst2, h2, es2, ed2);

  // layer 2 aggregation + ELU + classifier dot (z per node)
  k_agg2<<<(NT + 7) / 8, 256, 0, stream>>>(row_ptr, adj, es2, ed2, h2, b2, Wc, z);

  // pool + bias
  k_poolz<<<GT, 256, 0, stream>>>(z, batch, bc, out);
}